// Round 3
// baseline (211.777 us; speedup 1.0000x reference)
//
#include <hip/hip_runtime.h>
#include <cstdint>
#include <cstddef>

// Problem constants (from reference setup_inputs)
#define BB 64
#define TT 256
#define DD 512
#define BK 32
#define TILEM 128

typedef short bf16x8 __attribute__((ext_vector_type(8)));  // 8 bf16 in 4 VGPRs
typedef float f32x4  __attribute__((ext_vector_type(4)));  // MFMA acc / 16B loads
typedef int   i32x4  __attribute__((ext_vector_type(4)));  // 16B LDS store

// fp32 -> bf16, round-half-up (1 add + shift; bias 2^-17, irrelevant vs threshold)
static __device__ __forceinline__ unsigned short f2bf(float x) {
  unsigned u = __builtin_bit_cast(unsigned, x) + 0x8000u;
  return (unsigned short)(u >> 16);
}

// SYMMETRY: out_r[b] symmetric, out_i[b] antisymmetric -> only the 10
// lower-triangular 128x128 tiles per batch are computed (vs 16). Off-diagonal
// blocks also write the mirrored tile (out_r copied, out_i negated) via a
// wave-private LDS transpose.
//
// Round-2 lesson (counters): 79.5us with MfmaUtil 10% / VALUBusy 13% / L2-read
// service 3.2 TB/s -> memory-LATENCY bound on staging (64 scalar 4B loads per
// thread per iter, occupancy capped at 2 blocks/CU by the 128-f32 accumulator).
// This version stages with 16x float4 row loads + in-register transpose (4x
// fewer load issues). The k-contiguous LDS writes would be 8-way bank
// conflicted; a granule swizzle (algebraically: rotate dd-write order by
// (q>>1)&3, matching XOR on the fragment-read address) makes both sides
// conflict-free.
__global__ __launch_bounds__(256, 2)
void ComplexMixture_54838142435828_kernel(const float* __restrict__ re,
                                          const float* __restrict__ im,
                                          const float* __restrict__ wt,
                                          float* __restrict__ out) {
  // Unified LDS: staging arrays during k-loop; first 32 KB reused by the
  // per-wave epilogue transpose (8 KB per wave, wave-private).
  __shared__ __attribute__((aligned(16))) char smem[33792];
  unsigned short* sAr = (unsigned short*)(smem);           // w*R, rows d   (8 KB)
  unsigned short* sAi = (unsigned short*)(smem + 8192);    // w*I, rows d   (8 KB)
  unsigned short* sBr = (unsigned short*)(smem + 16384);   // R, cols e     (8 KB)
  unsigned short* sBi = (unsigned short*)(smem + 24576);   // I, cols i     (8 KB)
  float*          sw  = (float*)(smem + 32768);            // weights       (1 KB)

  const int tid = threadIdx.x;

  // ---- XCD-cluster swizzle + triangular tile map ----
  const int L = blockIdx.x;        // 0..639
  const int c = L & 7;             // XCD (round-robin dispatch by linear id)
  const int s = L >> 3;            // 0..79 within XCD
  const int b  = c * 8 + s / 10;   // 8 batches per XCD, 10 tiles each
  const int t  = s % 10;           // triangular tile id 0..9
  const int ti = (t >= 6) ? 3 : (t >= 3) ? 2 : (t >= 1) ? 1 : 0;
  const int tj = t - ((ti * (ti + 1)) >> 1);   // ti >= tj always
  const int d0 = ti * TILEM;       // output row tile
  const int e0 = tj * TILEM;       // output col tile

  sw[tid] = wt[b * TT + tid];  // T == blockDim.x == 256; synced by loop-top barrier

  const int lane = tid & 63;
  const int wid  = tid >> 6;
  const int wm = (wid >> 1) * 64;  // wave row offset in tile
  const int wn = (wid & 1) * 64;   // wave col offset in tile
  const int quad = lane >> 4;      // selects k-octet (chunk)
  const int l16  = lane & 15;

  // ---- staging roles: thread = (d-quad q, k-half h, array, side) ----
  // side/arr are WAVE-uniform (bits 7,6 of tid) -> no divergence, SGPR bases.
  const int q     = tid & 31;         // d-quad within 128-col panel
  const int h     = (tid >> 5) & 1;   // k-half: rows kb..kb+15
  const int warr  = (tid >> 6) & 1;   // 0=real, 1=imag
  const int wside = tid >> 7;         // 0=A (d0 panel, w-scaled), 1=B (e0 panel, raw)
  unsigned short* dst = wside ? (warr ? sBi : sBr) : (warr ? sAi : sAr);
  const float* srcArr = warr ? im : re;
  const int panel = wside ? e0 : d0;  // diag tiles: e0==d0 -> side-1 loads hit L1/L2
  const int swm = (q >> 1) & 3;       // dd-rotation = write-side bank swizzle

  // fragment-read swizzle partner: XOR row bits 3,4 into bits 0,1
  const int l16b = l16 ^ ((l16 >> 3) & 1);

  f32x4 accR[4][4], accI[4][4];
  #pragma unroll
  for (int mt = 0; mt < 4; ++mt)
    #pragma unroll
    for (int nt = 0; nt < 4; ++nt) {
      accR[mt][nt] = (f32x4){0.f, 0.f, 0.f, 0.f};
      accI[mt][nt] = (f32x4){0.f, 0.f, 0.f, 0.f};
    }

  for (int kt = 0; kt < TT; kt += BK) {
    __syncthreads();  // prev iteration's LDS readers done (and sw init on iter 0)

    // -------- stage: 16x float4 row loads -> scale -> bf16 -> swizzled LDS ------
    const int kb = kt + h * 16;
    const float* rowPtr = srcArr + ((size_t)(b * TT + kb)) * DD + panel + q * 4;
    f32x4 v[16];
    #pragma unroll
    for (int k = 0; k < 16; ++k)
      v[k] = *(const f32x4*)(rowPtr + (size_t)k * DD);
    if (!wside) {  // wave-uniform: A-side scales by w[t]
      #pragma unroll
      for (int k = 0; k < 16; ++k)
        v[k] *= sw[kb + k];   // 2 distinct addrs per wave -> LDS broadcast, free
    }
    #pragma unroll
    for (int oc = 0; oc < 2; ++oc) {
      #pragma unroll
      for (int dd = 0; dd < 4; ++dd) {
        union { unsigned short hh[8]; i32x4 qq; } u;
        #pragma unroll
        for (int j = 0; j < 8; ++j)
          u.hh[j] = f2bf(v[oc * 8 + j][dd]);
        // granule = oct*128 + 4q + (dd ^ swm); 8 consecutive lanes cover 8
        // distinct granule-slots -> conflict-free b128 stores (verified alg.)
        const int g = ((2 * h + oc) * 128 + 4 * q + (dd ^ swm));
        *(i32x4*)&dst[g * 8] = u.qq;
      }
    }
    __syncthreads();

    // -------- compute: one MFMA K=32 step ---------------------------------------
    // A frag: A[m=lane&15][k=quad*8+j] (m89-verified); read addr carries the
    // matching swizzle: row' = wm + tt*16 + (l16b ^ ((tt&1)<<1)).
    bf16x8 aR[4], aI[4], bR[4], bI[4];
    #pragma unroll
    for (int tt = 0; tt < 4; ++tt) {
      const int rsw = l16b ^ ((tt & 1) << 1);
      const int ga = (quad * 128 + wm + tt * 16 + rsw) * 8;
      const int gb = (quad * 128 + wn + tt * 16 + rsw) * 8;
      aR[tt] = *(const bf16x8*)&sAr[ga];
      aI[tt] = *(const bf16x8*)&sAi[ga];
      bR[tt] = *(const bf16x8*)&sBr[gb];
      bI[tt] = *(const bf16x8*)&sBi[gb];
    }
    #pragma unroll
    for (int mt = 0; mt < 4; ++mt) {
      const bf16x8 aRn = aR[mt] ^ (bf16x8)((short)0x8000);  // -(w*R) via sign flip
      #pragma unroll
      for (int nt = 0; nt < 4; ++nt) {
        accR[mt][nt] = __builtin_amdgcn_mfma_f32_16x16x32_bf16(aR[mt], bR[nt], accR[mt][nt], 0, 0, 0);
        accR[mt][nt] = __builtin_amdgcn_mfma_f32_16x16x32_bf16(aI[mt], bI[nt], accR[mt][nt], 0, 0, 0);
        accI[mt][nt] = __builtin_amdgcn_mfma_f32_16x16x32_bf16(aI[mt], bR[nt], accI[mt][nt], 0, 0, 0);
        accI[mt][nt] = __builtin_amdgcn_mfma_f32_16x16x32_bf16(aRn,    bI[nt], accI[mt][nt], 0, 0, 0);
      }
    }
  }

  // ONE barrier: last iteration's staging-LDS readers must finish before the
  // slab region (aliasing sAr..sBi) is reused. Placed BEFORE any global store,
  // so the store stream never hits a vmcnt(0) drain.
  __syncthreads();

  // ---------------- epilogue 1: direct tile (C/D layout col=lane&15, row=quad*4+r) --
  const size_t NOFF = (size_t)BB * DD * DD;  // out_i offset in flat tuple output
  #pragma unroll
  for (int mt = 0; mt < 4; ++mt) {
    #pragma unroll
    for (int r = 0; r < 4; ++r) {
      const int drow = d0 + wm + mt * 16 + quad * 4 + r;
      const size_t rowOff = ((size_t)(b * DD + drow)) * DD;
      #pragma unroll
      for (int nt = 0; nt < 4; ++nt) {
        const int ecol = e0 + wn + nt * 16 + l16;
        out[rowOff + ecol]        = accR[mt][nt][r];
        out[NOFF + rowOff + ecol] = accI[mt][nt][r];
      }
    }
  }

  // ---------------- epilogue 2: mirrored tile (off-diagonal blocks only) ------------
  // out_r[b][e][d] = out_r[b][d][e];  out_i[b][e][d] = -out_i[b][d][e].
  // WAVE-PRIVATE 8 KB slab (no barriers; same-wave DS ordering via lgkmcnt).
  if (ti != tj) {
    float* tbR = (float*)(smem + wid * 8192);  // 4 KB per wave
    float* tbI = tbR + 1024;                   // 4 KB per wave
    #pragma unroll
    for (int mt = 0; mt < 4; ++mt) {
      #pragma unroll
      for (int nt = 0; nt < 4; ++nt) {
        #pragma unroll
        for (int r = 0; r < 4; ++r) {
          const int a = (quad * 4 + r) * 64 + nt * 16 + l16;
          tbR[a] = accR[mt][nt][r];
          tbI[a] = -accI[mt][nt][r];
        }
      }
      const size_t trOff = ((size_t)(b * DD + e0 + wn + lane)) * DD
                         + (size_t)(d0 + wm + mt * 16);
      #pragma unroll
      for (int j = 0; j < 4; ++j) {
        f32x4 vr, vi;
        #pragma unroll
        for (int qq = 0; qq < 4; ++qq) {
          vr[qq] = tbR[(j * 4 + qq) * 64 + lane];
          vi[qq] = tbI[(j * 4 + qq) * 64 + lane];
        }
        *(f32x4*)&out[trOff + j * 4]        = vr;
        *(f32x4*)&out[NOFF + trOff + j * 4] = vi;
      }
    }
  }
}

extern "C" void kernel_launch(void* const* d_in, const int* in_sizes, int n_in,
                              void* d_out, int out_size, void* d_ws, size_t ws_size,
                              hipStream_t stream) {
  const float* re = (const float*)d_in[0];
  const float* im = (const float*)d_in[1];
  const float* wt = (const float*)d_in[2];
  float* out = (float*)d_out;
  ComplexMixture_54838142435828_kernel<<<dim3(640), dim3(256), 0, stream>>>(re, im, wt, out);
}

// Round 5
// 207.470 us; speedup vs baseline: 1.0208x; 1.0208x over previous
//
#include <hip/hip_runtime.h>
#include <cstdint>
#include <cstddef>

// Problem constants (from reference setup_inputs)
#define BB 64
#define TT 256
#define DD 512
#define BK 32
#define TILEM 128
#define NITER (TT / BK)

typedef short bf16x8 __attribute__((ext_vector_type(8)));  // 8 bf16 in 4 VGPRs
typedef float f32x4  __attribute__((ext_vector_type(4)));  // MFMA acc / 16B loads
typedef int   i32x4  __attribute__((ext_vector_type(4)));  // 16B LDS store

// fp32 -> bf16, round-half-up (1 add + shift; bias 2^-17, irrelevant vs threshold)
static __device__ __forceinline__ unsigned short f2bf(float x) {
  unsigned u = __builtin_bit_cast(unsigned, x) + 0x8000u;
  return (unsigned short)(u >> 16);
}

// SYMMETRY: out_r symmetric, out_i antisymmetric -> 10 lower-tri 128x128 tiles/batch.
//
// Round-3 lesson: latency-bound, not issue-bound. __syncthreads() lowers to
// s_waitcnt vmcnt(0)+s_barrier, draining any prefetch. This version:
//  - 8-wave (512-thr) blocks, wave tile 64x32 -> acc 64 f32, prefetch regs 32.
//  - double-buffered LDS, 1-deep pipeline: issue next iter's global loads,
//    then ONE fused asm {s_waitcnt lgkmcnt(0); s_barrier} (vmcnt NOT drained:
//    prefetch stays in flight; fused asm also stops LLVM hoisting ds_reads
//    above the barrier -- s_barrier intrinsic is IntrNoMem), then ds_read+MFMA
//    (covers load latency), then convert+ds_write the other buffer.
//  - conflict-free XOR granule swizzle, re-derived this round:
//    write granule col = 4*tq + (dd ^ (tq&3) ^ ((tq>>2)&1)) covers all 8
//    bank-groups per 8 consecutive lanes; read row r uses the identical
//    formula with d=r (incl. the (r>>4)&1 term).
//  - epilogue via wave-private LDS slab: ALL global stores are f32x4 full-line.
__global__ __launch_bounds__(512, 2)
void ComplexMixture_54838142435828_kernel(const float* __restrict__ re,
                                          const float* __restrict__ im,
                                          const float* __restrict__ wt,
                                          float* __restrict__ out) {
  // Two 32-KB staging buffers; each: [A-re|A-im|B-re|B-im] sub-panels of 8 KB.
  // Sub-panel = 512 granules of 16 B; granule (oct,col) = 8 bf16 along t.
  __shared__ __attribute__((aligned(16))) char smem[65536];

  const int tid = threadIdx.x;

  // ---- XCD-cluster swizzle + triangular tile map ----
  const int L = blockIdx.x;        // 0..639
  const int c = L & 7;             // XCD (round-robin dispatch by linear id)
  const int s = L >> 3;            // 0..79 within XCD
  const int b  = c * 8 + s / 10;   // 8 batches per XCD, 10 tiles each
  const int t  = s % 10;           // triangular tile id 0..9
  const int ti = (t >= 6) ? 3 : (t >= 3) ? 2 : (t >= 1) ? 1 : 0;
  const int tj = t - ((ti * (ti + 1)) >> 1);   // ti >= tj
  const int d0 = ti * TILEM;
  const int e0 = tj * TILEM;

  const int lane = tid & 63;
  const int wid  = tid >> 6;          // 0..7
  const int wm   = (wid >> 2) * 64;   // wave row offset (2 rows of waves)
  const int wn   = (wid & 3) * 32;    // wave col offset (4 cols of waves)
  const int quad = lane >> 4;
  const int l16  = lane & 15;

  // ---- staging roles: g picks sub-panel (wave-uniform: 2 waves per g) ----
  const int g  = tid >> 7;            // 0:A-re 1:A-im 2:B-re 3:B-im
  const int tq = tid & 31;            // col-quad within 128-col panel
  const int th = (tid >> 5) & 3;      // t-octet
  const bool aside = (g < 2);
  const float* src = (g & 1) ? im : re;
  const int panel  = aside ? d0 : e0; // diag tiles: e0==d0 -> B loads hit L1/L2
  const int subOff = g * 8192;

  // write granule byte offsets (conflict-free: col = 4tq + (dd^(tq&3)^((tq>>2)&1)))
  int wgo[4];
  #pragma unroll
  for (int dd = 0; dd < 4; ++dd)
    wgo[dd] = (th * 128 + 4 * tq + (dd ^ (tq & 3) ^ ((tq >> 2) & 1))) * 16;

  const size_t colBase = (size_t)(b * TT) * DD + panel + tq * 4;
  const float* wtb = wt + b * TT;

  f32x4 accR[4][2], accI[4][2];
  #pragma unroll
  for (int mt = 0; mt < 4; ++mt)
    #pragma unroll
    for (int nt = 0; nt < 2; ++nt) {
      accR[mt][nt] = (f32x4){0.f, 0.f, 0.f, 0.f};
      accI[mt][nt] = (f32x4){0.f, 0.f, 0.f, 0.f};
    }

  f32x4 v[8];
  f32x4 w0 = (f32x4){1.f,1.f,1.f,1.f}, w1 = w0;

  // ---------------- prologue: load kt=0, stage into buffer 0 -----------------
  #pragma unroll
  for (int k = 0; k < 8; ++k)
    v[k] = *(const f32x4*)(src + colBase + (size_t)(th * 8 + k) * DD);
  if (aside) {
    w0 = *(const f32x4*)(wtb + th * 8);
    w1 = *(const f32x4*)(wtb + th * 8 + 4);
  }
  {
    char* wb = smem + subOff;
    if (aside) {
      #pragma unroll
      for (int k = 0; k < 4; ++k) v[k] *= w0[k];
      #pragma unroll
      for (int k = 0; k < 4; ++k) v[k + 4] *= w1[k];
    }
    #pragma unroll
    for (int dd = 0; dd < 4; ++dd) {
      union { unsigned short hh[8]; i32x4 q; } u;
      #pragma unroll
      for (int j = 0; j < 8; ++j) u.hh[j] = f2bf(v[j][dd]);
      *(i32x4*)(wb + wgo[dd]) = u.q;
    }
  }

  // ---------------- pipelined k-loop (8 iters, fully unrolled) ---------------
  #pragma unroll
  for (int it = 0; it < NITER; ++it) {
    const int ktn = it * BK + BK;
    const int rbo = (it & 1) * 32768;   // read-buffer byte offset (compile-time)

    if (ktn < TT) {  // issue NEXT iter's global loads; they stay in flight
      #pragma unroll
      for (int k = 0; k < 8; ++k)
        v[k] = *(const f32x4*)(src + colBase + (size_t)(ktn + th * 8 + k) * DD);
      if (aside) {
        w0 = *(const f32x4*)(wtb + ktn + th * 8);
        w1 = *(const f32x4*)(wtb + ktn + th * 8 + 4);
      }
    }

    // Release our ds_writes + barrier, in ONE asm: vmcnt NOT drained (global
    // prefetch stays in flight) and no memory op can cross in either direction.
    asm volatile("s_waitcnt lgkmcnt(0)\n\ts_barrier" ::: "memory");

    // fragment reads from buf[it&1] (read swizzle == write swizzle with d=r)
    const char* rb = smem + rbo;
    bf16x8 aR[4], aI[4], bR[2], bI[2];
    #pragma unroll
    for (int mt = 0; mt < 4; ++mt) {
      const int r  = wm + mt * 16 + l16;
      const int gi = (quad * 128 + (r & ~3) +
                      ((r & 3) ^ ((r >> 2) & 3) ^ ((r >> 4) & 1))) * 16;
      aR[mt] = *(const bf16x8*)(rb + gi);
      aI[mt] = *(const bf16x8*)(rb + 8192 + gi);
    }
    #pragma unroll
    for (int nt = 0; nt < 2; ++nt) {
      const int r  = wn + nt * 16 + l16;
      const int gi = (quad * 128 + (r & ~3) +
                      ((r & 3) ^ ((r >> 2) & 3) ^ ((r >> 4) & 1))) * 16;
      bR[nt] = *(const bf16x8*)(rb + 16384 + gi);
      bI[nt] = *(const bf16x8*)(rb + 24576 + gi);
    }

    #pragma unroll
    for (int mt = 0; mt < 4; ++mt) {
      const bf16x8 aRn = aR[mt] ^ (bf16x8)((short)0x8000);  // -(w*R) sign flip
      #pragma unroll
      for (int nt = 0; nt < 2; ++nt) {
        accR[mt][nt] = __builtin_amdgcn_mfma_f32_16x16x32_bf16(aR[mt], bR[nt], accR[mt][nt], 0, 0, 0);
        accR[mt][nt] = __builtin_amdgcn_mfma_f32_16x16x32_bf16(aI[mt], bI[nt], accR[mt][nt], 0, 0, 0);
        accI[mt][nt] = __builtin_amdgcn_mfma_f32_16x16x32_bf16(aI[mt], bR[nt], accI[mt][nt], 0, 0, 0);
        accI[mt][nt] = __builtin_amdgcn_mfma_f32_16x16x32_bf16(aRn,    bI[nt], accI[mt][nt], 0, 0, 0);
      }
    }

    if (ktn < TT) {  // convert (vmcnt auto-waited here) + write the other buffer
      char* wb = smem + ((it & 1) ^ 1) * 32768 + subOff;
      if (aside) {
        #pragma unroll
        for (int k = 0; k < 4; ++k) v[k] *= w0[k];
        #pragma unroll
        for (int k = 0; k < 4; ++k) v[k + 4] *= w1[k];
      }
      #pragma unroll
      for (int dd = 0; dd < 4; ++dd) {
        union { unsigned short hh[8]; i32x4 q; } u;
        #pragma unroll
        for (int j = 0; j < 8; ++j) u.hh[j] = f2bf(v[j][dd]);
        *(i32x4*)(wb + wgo[dd]) = u.q;
      }
    }
  }

  // ---------------- epilogue: slab-transposed f32x4 stores -------------------
  // Slab region = buffer 0 (last read at it=6; all waves passed the it=7
  // barrier only after consuming those reads -> safe without extra barrier).
  // Wave-private 4 KB: [16 d-rows][32 e-cols] f32, col swizzled ^(row>>2)<<3.
  const size_t NOFF = (size_t)BB * DD * DD;
  float* tbR = (float*)(smem + wid * 4096);
  float* tbI = tbR + 512;
  const bool offdiag = (ti != tj);

  #pragma unroll
  for (int mt = 0; mt < 4; ++mt) {
    // write slab: row = quad*4+r (d-local), col = nt*16+l16 (e-local)
    #pragma unroll
    for (int nt = 0; nt < 2; ++nt)
      #pragma unroll
      for (int r = 0; r < 4; ++r) {
        const int a = (quad * 4 + r) * 32 + ((nt * 16 + l16) ^ (quad << 3));
        tbR[a] = accR[mt][nt][r];
        tbI[a] = accI[mt][nt][r];
      }
    // direct tile: lane -> d-row lane>>2, e-chunk (lane&3)*8; full-line stores
    {
      const int rowD = lane >> 2;
      const int ech  = (lane & 3) * 8;
      const int a0   = rowD * 32 + (ech ^ ((rowD >> 2) << 3));
      const f32x4 r0 = *(const f32x4*)&tbR[a0];
      const f32x4 r1 = *(const f32x4*)&tbR[a0 + 4];
      const f32x4 i0 = *(const f32x4*)&tbI[a0];
      const f32x4 i1 = *(const f32x4*)&tbI[a0 + 4];
      const size_t ro = ((size_t)(b * DD + d0 + wm + mt * 16 + rowD)) * DD
                      + (size_t)(e0 + wn + ech);
      *(f32x4*)&out[ro]            = r0;
      *(f32x4*)&out[ro + 4]        = r1;
      *(f32x4*)&out[NOFF + ro]     = i0;
      *(f32x4*)&out[NOFF + ro + 4] = i1;
    }
    // mirrored tile (off-diag): lane -> e-row lane&31, d-half lane>>5
    if (offdiag) {
      const int er = lane & 31;
      const int hf = lane >> 5;
      f32x4 rr0, rr1, ii0, ii1;
      #pragma unroll
      for (int j2 = 0; j2 < 4; ++j2) {
        const int p0 = hf * 8 + j2;
        const int p1 = hf * 8 + 4 + j2;
        const int a0 = p0 * 32 + (er ^ ((p0 >> 2) << 3));
        const int a1 = p1 * 32 + (er ^ ((p1 >> 2) << 3));
        rr0[j2] =  tbR[a0];
        rr1[j2] =  tbR[a1];
        ii0[j2] = -tbI[a0];
        ii1[j2] = -tbI[a1];
      }
      const size_t mo = ((size_t)(b * DD + e0 + wn + er)) * DD
                      + (size_t)(d0 + wm + mt * 16 + hf * 8);
      *(f32x4*)&out[mo]            = rr0;
      *(f32x4*)&out[mo + 4]        = rr1;
      *(f32x4*)&out[NOFF + mo]     = ii0;
      *(f32x4*)&out[NOFF + mo + 4] = ii1;
    }
  }
}

extern "C" void kernel_launch(void* const* d_in, const int* in_sizes, int n_in,
                              void* d_out, int out_size, void* d_ws, size_t ws_size,
                              hipStream_t stream) {
  const float* re = (const float*)d_in[0];
  const float* im = (const float*)d_in[1];
  const float* wt = (const float*)d_in[2];
  float* out = (float*)d_out;
  ComplexMixture_54838142435828_kernel<<<dim3(640), dim3(512), 0, stream>>>(re, im, wt, out);
}